// Round 16
// baseline (1304.745 us; speedup 1.0000x reference)
//
#include <hip/hip_runtime.h>
#include <hip/hip_bf16.h>

#define F_IN 64
#define HID 64
#define NCLS 10
#define NG 512

// bf16 helpers (RNE pack, cheap unpack)
__device__ __forceinline__ unsigned short f2bf(float f) {
    unsigned int u = __float_as_uint(f);
    unsigned int r = (u + 0x7fffu + ((u >> 16) & 1u)) >> 16;
    return (unsigned short)r;
}
__device__ __forceinline__ float bf2f(unsigned short h) {
    return __uint_as_float(((unsigned int)h) << 16);
}
__device__ __forceinline__ float4 bf4(ushort4 u) {
    return make_float4(bf2f(u.x), bf2f(u.y), bf2f(u.z), bf2f(u.w));
}

// ---------------------------------------------------------------------------
// Fused: UNsharded count (deg is 200 KB of atomics — no store-amp issue;
// sharding only paid for csr_src's plain stores) + gbound.
__global__ void count_gbound_kernel(const int* __restrict__ ei, int* __restrict__ deg,
                                    const int* __restrict__ batch, int* __restrict__ gstart,
                                    int E_, int N_, int cblk) {
    int b = blockIdx.x;
    if (b < cblk) {
        int e = b * 256 + threadIdx.x;
        if (e < E_) atomicAdd(&deg[ei[E_ + e]], 1);
    } else {
        int i = (b - cblk) * 256 + threadIdx.x;
        if (i >= N_) return;
        int bi = batch[i];
        int bprev = (i == 0) ? -1 : batch[i - 1];
        for (int g = bprev + 1; g <= bi; ++g) gstart[g] = i;
        if (i == N_ - 1)
            for (int g = bi + 1; g <= NG; ++g) gstart[g] = N_;
    }
}

// ---------------------------------------------------------------------------
__global__ void scan_local_kernel(const int* __restrict__ deg, int* __restrict__ rs_part,
                                  int* __restrict__ blksum, int N_) {
    __shared__ int tmp[256];
    int t = threadIdx.x;
    int i = blockIdx.x * 256 + t;
    int v = (i < N_) ? deg[i] : 0;
    tmp[t] = v;
    __syncthreads();
    for (int off = 1; off < 256; off <<= 1) {
        int add = (t >= off) ? tmp[t - off] : 0;
        __syncthreads();
        tmp[t] += add;
        __syncthreads();
    }
    if (i < N_) rs_part[i] = tmp[t] - v;
    if (t == 255) blksum[blockIdx.x] = tmp[255];
}

__global__ void scan_final_kernel(const int* __restrict__ rs_part,
                                  const int* __restrict__ blksum,
                                  int* __restrict__ rs, int* __restrict__ cursor,
                                  int N_, int E_, int nblk) {
    __shared__ int tmp[256];
    int t = threadIdx.x;
    int b = blockIdx.x;
    tmp[t] = (t < b && t < nblk) ? blksum[t] : 0;
    __syncthreads();
    for (int off = 128; off > 0; off >>= 1) {
        if (t < off) tmp[t] += tmp[t + off];
        __syncthreads();
    }
    int off0 = tmp[0];
    int i = b * 256 + t;
    if (i < N_) {
        int v = rs_part[i] + off0;
        rs[i] = v;
        cursor[i] = v;
    }
    if (i == 0) rs[N_] = E_;
}

// ---------------------------------------------------------------------------
// XCD-sharded scatter (verified win, R13->R14).
__global__ void scatter_kernel(const int* __restrict__ ei, int* __restrict__ cursor,
                               int* __restrict__ csr_src, int E_, int N_, int csh) {
    int shard = blockIdx.x & 7;
    int chunk = blockIdx.x >> 3;
    int slice = (N_ + 7) >> 3;
    int lo = shard * slice, hi = min(N_, lo + slice);
    int stride = csh * 256;
    for (int e = chunk * 256 + threadIdx.x; e < E_; e += stride) {
        int d = ei[E_ + e];
        if (d >= lo && d < hi) {
            int pos = atomicAdd(&cursor[d], 1);
            csr_src[pos] = ei[e];
        }
    }
}

// ---------------------------------------------------------------------------
// GEMM1: x @ Wl1 -> xl1 (bf16), @ Wr1 -> xr1 (bf16). k-tiled x4:
// 8 broadcast ds_read_b128 per 4 k-steps instead of 32 scalar LDS reads.
__global__ void gemm1_kernel(const float* __restrict__ x,
                             const float* __restrict__ Wl,
                             const float* __restrict__ Wr,
                             unsigned short* __restrict__ xlb,
                             unsigned short* __restrict__ xrb,
                             int N_) {
    __shared__ float xs[8 * 64];
    int r0 = blockIdx.x * 8;
    int t = threadIdx.x;
    for (int i = t; i < 8 * 64; i += 256) {
        int r = i >> 6;
        xs[i] = (r0 + r < N_) ? x[(long)(r0 + r) * 64 + (i & 63)] : 0.f;
    }
    __syncthreads();
    const float* W = (t < 128) ? Wl : Wr;
    int col = t & 127;
    float acc[8] = {0.f, 0.f, 0.f, 0.f, 0.f, 0.f, 0.f, 0.f};
    for (int k = 0; k < 64; k += 4) {
        float w0 = W[k * 128 + col];
        float w1 = W[(k + 1) * 128 + col];
        float w2 = W[(k + 2) * 128 + col];
        float w3 = W[(k + 3) * 128 + col];
#pragma unroll
        for (int r = 0; r < 8; ++r) {
            float4 xv = *(const float4*)(xs + r * 64 + k);
            acc[r] += xv.x * w0 + xv.y * w1 + xv.z * w2 + xv.w * w3;
        }
    }
    unsigned short* out = (t < 128) ? xlb : xrb;
#pragma unroll
    for (int r = 0; r < 8; ++r)
        if (r0 + r < N_) out[(long)(r0 + r) * 128 + col] = f2bf(acc[r]);
}

// ---------------------------------------------------------------------------
// GEMM2: h1 (bf16) @ Wl2 -> xl2 (bf16), @ Wr2 -> xr2 (bf16). k-tiled x4.
__global__ void gemm2_kernel(const unsigned short* __restrict__ h1,
                             const float* __restrict__ Wl,
                             const float* __restrict__ Wr,
                             unsigned short* __restrict__ xlb,
                             unsigned short* __restrict__ xrb,
                             int N_) {
    __shared__ float hs[8 * 128];
    int r0 = blockIdx.x * 8;
    int t = threadIdx.x;
    for (int j = t; j < 256; j += 128) {
        int row = j >> 5, c4 = j & 31;
        float4 v = make_float4(0.f, 0.f, 0.f, 0.f);
        if (r0 + row < N_)
            v = bf4(*(const ushort4*)(h1 + (long)(r0 + row) * 128 + c4 * 4));
        *(float4*)(hs + row * 128 + c4 * 4) = v;
    }
    __syncthreads();
    const float* W = (t < 64) ? Wl : Wr;
    int col = t & 63;
    float acc[8] = {0.f, 0.f, 0.f, 0.f, 0.f, 0.f, 0.f, 0.f};
    for (int k = 0; k < 128; k += 4) {
        float w0 = W[k * 64 + col];
        float w1 = W[(k + 1) * 64 + col];
        float w2 = W[(k + 2) * 64 + col];
        float w3 = W[(k + 3) * 64 + col];
#pragma unroll
        for (int r = 0; r < 8; ++r) {
            float4 hv = *(const float4*)(hs + r * 128 + k);
            acc[r] += hv.x * w0 + hv.y * w1 + hv.z * w2 + hv.w * w3;
        }
    }
    unsigned short* out = (t < 64) ? xlb : xrb;
#pragma unroll
    for (int r = 0; r < 8; ++r)
        if (r0 + r < N_) out[(long)(r0 + r) * 64 + col] = f2bf(acc[r]);
}

// ---------------------------------------------------------------------------
// Fused GATv2 layer 1, HEAD-MERGED, all-bf16. Main loop = full 4-edge groups
// with no masks + 32-bit gather offsets; one masked tail group (2nd depth
// skipped by wave-uniform branch).
__global__ void gat1_kernel(const unsigned short* __restrict__ xlb,
                            unsigned short* __restrict__ xrb,  // in: xr1, out: h1
                            const float* __restrict__ att,
                            const float* __restrict__ b1,
                            const int* __restrict__ rs,
                            const int* __restrict__ csr_src,
                            int N_) {
    int d = (int)(((long)blockIdx.x * blockDim.x + threadIdx.x) >> 6);
    int lane = threadIdx.x & 63;
    if (d >= N_) return;
    int slot = lane >> 5;     // 0..1
    int c8 = lane & 31;       // channel group: channels c8*4..+3 of 128
    unsigned coff = (unsigned)(c8 << 2);
    long rowoff = (long)d * 128 + c8 * 4;
    const float4 xr4 = bf4(*(const ushort4*)(xrb + rowoff));
    const float4 at4 = *(const float4*)(att + c8 * 4);

    int k0 = rs[d], k1 = rs[d + 1];
    int cnt = k1 - k0 + 1;

    float4 acc = make_float4(0.f, 0.f, 0.f, 0.f);
    float den = 0.f;
    for (int c0 = 0; c0 < cnt; c0 += 64) {
        int wl = c0 + lane;
        int myidx = (wl >= 1 && wl < cnt) ? csr_src[k0 + wl - 1] : d;
        int lim = min(64, cnt - c0);
        int pfull = lim & ~3;
        int p = 0;
        for (; p < pfull; p += 4) {      // all 4 edges valid: no masks
            int s0 = __shfl(myidx, p + slot, 64);
            int s1 = __shfl(myidx, p + 2 + slot, 64);
            float4 a0 = bf4(*(const ushort4*)(xlb + (((unsigned)s0 << 7) + coff)));
            float4 a1 = bf4(*(const ushort4*)(xlb + (((unsigned)s1 << 7) + coff)));
            float t, p0, p1;
            t = a0.x + xr4.x; t = fmaxf(t, 0.2f * t); p0  = at4.x * t;
            t = a0.y + xr4.y; t = fmaxf(t, 0.2f * t); p0 += at4.y * t;
            t = a0.z + xr4.z; t = fmaxf(t, 0.2f * t); p0 += at4.z * t;
            t = a0.w + xr4.w; t = fmaxf(t, 0.2f * t); p0 += at4.w * t;
            t = a1.x + xr4.x; t = fmaxf(t, 0.2f * t); p1  = at4.x * t;
            t = a1.y + xr4.y; t = fmaxf(t, 0.2f * t); p1 += at4.y * t;
            t = a1.z + xr4.z; t = fmaxf(t, 0.2f * t); p1 += at4.z * t;
            t = a1.w + xr4.w; t = fmaxf(t, 0.2f * t); p1 += at4.w * t;
            p0 += __shfl_xor(p0, 1, 64);  p1 += __shfl_xor(p1, 1, 64);
            p0 += __shfl_xor(p0, 2, 64);  p1 += __shfl_xor(p1, 2, 64);
            p0 += __shfl_xor(p0, 4, 64);  p1 += __shfl_xor(p1, 4, 64);
            p0 += __shfl_xor(p0, 8, 64);  p1 += __shfl_xor(p1, 8, 64);
            float w0 = __expf(p0);
            float w1 = __expf(p1);
            acc.x += w0 * a0.x + w1 * a1.x;
            acc.y += w0 * a0.y + w1 * a1.y;
            acc.z += w0 * a0.z + w1 * a1.z;
            acc.w += w0 * a0.w + w1 * a1.w;
            den += w0 + w1;
        }
        if (p < lim) {                   // masked tail group
            int e0 = p + slot;
            int s0 = __shfl(myidx, e0, 64);
            float4 a0 = bf4(*(const ushort4*)(xlb + (((unsigned)s0 << 7) + coff)));
            float t, p0;
            t = a0.x + xr4.x; t = fmaxf(t, 0.2f * t); p0  = at4.x * t;
            t = a0.y + xr4.y; t = fmaxf(t, 0.2f * t); p0 += at4.y * t;
            t = a0.z + xr4.z; t = fmaxf(t, 0.2f * t); p0 += at4.z * t;
            t = a0.w + xr4.w; t = fmaxf(t, 0.2f * t); p0 += at4.w * t;
            p0 += __shfl_xor(p0, 1, 64);
            p0 += __shfl_xor(p0, 2, 64);
            p0 += __shfl_xor(p0, 4, 64);
            p0 += __shfl_xor(p0, 8, 64);
            float w0 = (e0 < lim) ? __expf(p0) : 0.f;
            acc.x += w0 * a0.x; acc.y += w0 * a0.y;
            acc.z += w0 * a0.z; acc.w += w0 * a0.w;
            den += w0;
            if (p + 2 < lim) {           // wave-uniform: 2nd depth exists
                int e1 = p + 2 + slot;
                int s1 = __shfl(myidx, e1, 64);
                float4 a1 = bf4(*(const ushort4*)(xlb + (((unsigned)s1 << 7) + coff)));
                float p1;
                t = a1.x + xr4.x; t = fmaxf(t, 0.2f * t); p1  = at4.x * t;
                t = a1.y + xr4.y; t = fmaxf(t, 0.2f * t); p1 += at4.y * t;
                t = a1.z + xr4.z; t = fmaxf(t, 0.2f * t); p1 += at4.z * t;
                t = a1.w + xr4.w; t = fmaxf(t, 0.2f * t); p1 += at4.w * t;
                p1 += __shfl_xor(p1, 1, 64);
                p1 += __shfl_xor(p1, 2, 64);
                p1 += __shfl_xor(p1, 4, 64);
                p1 += __shfl_xor(p1, 8, 64);
                float w1 = (e1 < lim) ? __expf(p1) : 0.f;
                acc.x += w1 * a1.x; acc.y += w1 * a1.y;
                acc.z += w1 * a1.z; acc.w += w1 * a1.w;
                den += w1;
            }
        }
    }
    acc.x += __shfl_xor(acc.x, 32, 64);
    acc.y += __shfl_xor(acc.y, 32, 64);
    acc.z += __shfl_xor(acc.z, 32, 64);
    acc.w += __shfl_xor(acc.w, 32, 64);
    den   += __shfl_xor(den, 32, 64);
    if (slot == 0) {
        const float4 b4 = *(const float4*)(b1 + c8 * 4);
        float inv = 1.f / den;
        float4 v;
        v.x = acc.x * inv + b4.x; v.x = (v.x > 0.f) ? v.x : __expf(v.x) - 1.f;
        v.y = acc.y * inv + b4.y; v.y = (v.y > 0.f) ? v.y : __expf(v.y) - 1.f;
        v.z = acc.z * inv + b4.z; v.z = (v.z > 0.f) ? v.z : __expf(v.z) - 1.f;
        v.w = acc.w * inv + b4.w; v.w = (v.w > 0.f) ? v.w : __expf(v.w) - 1.f;
        ushort4 o;
        o.x = f2bf(v.x); o.y = f2bf(v.y); o.z = f2bf(v.z); o.w = f2bf(v.w);
        *(ushort4*)(xrb + rowoff) = o;   // h1 in place (bf16)
    }
}

// ---------------------------------------------------------------------------
// Fused GATv2 layer 2, all-bf16. Same main/tail split (4 slots, groups of 8).
__global__ void gat2_kernel(const unsigned short* __restrict__ xlb,
                            const unsigned short* __restrict__ xrb,
                            const float* __restrict__ att,
                            const float* __restrict__ b2,
                            const int* __restrict__ rs,
                            const int* __restrict__ csr_src,
                            unsigned short* __restrict__ h2,
                            int N_) {
    int d = (int)(((long)blockIdx.x * blockDim.x + threadIdx.x) >> 6);
    int lane = threadIdx.x & 63;
    if (d >= N_) return;
    int g = lane >> 4;        // 0..3
    int c4 = lane & 15;
    unsigned coff = (unsigned)(c4 << 2);
    long rowoff = (long)d * 64 + c4 * 4;
    const float4 xr4 = bf4(*(const ushort4*)(xrb + rowoff));
    const float4 at4 = *(const float4*)(att + c4 * 4);

    int k0 = rs[d], k1 = rs[d + 1];
    int cnt = k1 - k0 + 1;

    float4 acc = make_float4(0.f, 0.f, 0.f, 0.f);
    float den = 0.f;
    for (int c0 = 0; c0 < cnt; c0 += 64) {
        int wl = c0 + lane;
        int myidx = (wl >= 1 && wl < cnt) ? csr_src[k0 + wl - 1] : d;
        int lim = min(64, cnt - c0);
        int pfull = lim & ~7;
        int p = 0;
        for (; p < pfull; p += 8) {      // 8 valid edges: no masks
            int s0 = __shfl(myidx, p + g, 64);
            int s1 = __shfl(myidx, p + 4 + g, 64);
            float4 a0 = bf4(*(const ushort4*)(xlb + (((unsigned)s0 << 6) + coff)));
            float4 a1 = bf4(*(const ushort4*)(xlb + (((unsigned)s1 << 6) + coff)));
            float t, p0, p1;
            t = a0.x + xr4.x; t = fmaxf(t, 0.2f * t); p0  = at4.x * t;
            t = a0.y + xr4.y; t = fmaxf(t, 0.2f * t); p0 += at4.y * t;
            t = a0.z + xr4.z; t = fmaxf(t, 0.2f * t); p0 += at4.z * t;
            t = a0.w + xr4.w; t = fmaxf(t, 0.2f * t); p0 += at4.w * t;
            t = a1.x + xr4.x; t = fmaxf(t, 0.2f * t); p1  = at4.x * t;
            t = a1.y + xr4.y; t = fmaxf(t, 0.2f * t); p1 += at4.y * t;
            t = a1.z + xr4.z; t = fmaxf(t, 0.2f * t); p1 += at4.z * t;
            t = a1.w + xr4.w; t = fmaxf(t, 0.2f * t); p1 += at4.w * t;
            p0 += __shfl_xor(p0, 1, 64);  p1 += __shfl_xor(p1, 1, 64);
            p0 += __shfl_xor(p0, 2, 64);  p1 += __shfl_xor(p1, 2, 64);
            p0 += __shfl_xor(p0, 4, 64);  p1 += __shfl_xor(p1, 4, 64);
            p0 += __shfl_xor(p0, 8, 64);  p1 += __shfl_xor(p1, 8, 64);
            float w0 = __expf(p0);
            float w1 = __expf(p1);
            acc.x += w0 * a0.x + w1 * a1.x;
            acc.y += w0 * a0.y + w1 * a1.y;
            acc.z += w0 * a0.z + w1 * a1.z;
            acc.w += w0 * a0.w + w1 * a1.w;
            den += w0 + w1;
        }
        if (p < lim) {                   // masked tail group
            int e0 = p + g;
            int s0 = __shfl(myidx, e0, 64);
            float4 a0 = bf4(*(const ushort4*)(xlb + (((unsigned)s0 << 6) + coff)));
            float t, p0;
            t = a0.x + xr4.x; t = fmaxf(t, 0.2f * t); p0  = at4.x * t;
            t = a0.y + xr4.y; t = fmaxf(t, 0.2f * t); p0 += at4.y * t;
            t = a0.z + xr4.z; t = fmaxf(t, 0.2f * t); p0 += at4.z * t;
            t = a0.w + xr4.w; t = fmaxf(t, 0.2f * t); p0 += at4.w * t;
            p0 += __shfl_xor(p0, 1, 64);
            p0 += __shfl_xor(p0, 2, 64);
            p0 += __shfl_xor(p0, 4, 64);
            p0 += __shfl_xor(p0, 8, 64);
            float w0 = (e0 < lim) ? __expf(p0) : 0.f;
            acc.x += w0 * a0.x; acc.y += w0 * a0.y;
            acc.z += w0 * a0.z; acc.w += w0 * a0.w;
            den += w0;
            if (p + 4 < lim) {           // wave-uniform 2nd depth
                int e1 = p + 4 + g;
                int s1 = __shfl(myidx, e1, 64);
                float4 a1 = bf4(*(const ushort4*)(xlb + (((unsigned)s1 << 6) + coff)));
                float p1;
                t = a1.x + xr4.x; t = fmaxf(t, 0.2f * t); p1  = at4.x * t;
                t = a1.y + xr4.y; t = fmaxf(t, 0.2f * t); p1 += at4.y * t;
                t = a1.z + xr4.z; t = fmaxf(t, 0.2f * t); p1 += at4.z * t;
                t = a1.w + xr4.w; t = fmaxf(t, 0.2f * t); p1 += at4.w * t;
                p1 += __shfl_xor(p1, 1, 64);
                p1 += __shfl_xor(p1, 2, 64);
                p1 += __shfl_xor(p1, 4, 64);
                p1 += __shfl_xor(p1, 8, 64);
                float w1 = (e1 < lim) ? __expf(p1) : 0.f;
                acc.x += w1 * a1.x; acc.y += w1 * a1.y;
                acc.z += w1 * a1.z; acc.w += w1 * a1.w;
                den += w1;
            }
        }
    }
#pragma unroll
    for (int m = 16; m < 64; m <<= 1) {
        acc.x += __shfl_xor(acc.x, m, 64);
        acc.y += __shfl_xor(acc.y, m, 64);
        acc.z += __shfl_xor(acc.z, m, 64);
        acc.w += __shfl_xor(acc.w, m, 64);
        den   += __shfl_xor(den, m, 64);
    }
    if (g == 0) {
        const float4 b4 = *(const float4*)(b2 + c4 * 4);
        float inv = 1.f / den;
        ushort4 o;
        o.x = f2bf(acc.x * inv + b4.x);
        o.y = f2bf(acc.y * inv + b4.y);
        o.z = f2bf(acc.z * inv + b4.z);
        o.w = f2bf(acc.w * inv + b4.w);
        *(ushort4*)(h2 + rowoff) = o;
    }
}

// ---------------------------------------------------------------------------
// Segmented mean-pool (h2 bf16) + 64x10 classifier.
__global__ void pool_final_kernel(const unsigned short* __restrict__ h2,
                                  const int* __restrict__ gstart,
                                  const float* __restrict__ lin_w,
                                  const float* __restrict__ lin_b,
                                  float* __restrict__ out) {
    int g = blockIdx.x;
    int lane = threadIdx.x;
    int s = gstart[g], e = gstart[g + 1];
    float acc = 0.f;
    int i = s;
    for (; i + 3 < e; i += 4) {
        float v0 = bf2f(h2[(long)i * 64 + lane]);
        float v1 = bf2f(h2[(long)(i + 1) * 64 + lane]);
        float v2 = bf2f(h2[(long)(i + 2) * 64 + lane]);
        float v3 = bf2f(h2[(long)(i + 3) * 64 + lane]);
        acc += (v0 + v1) + (v2 + v3);
    }
    for (; i < e; ++i) acc += bf2f(h2[(long)i * 64 + lane]);
    float pc = acc / fmaxf((float)(e - s), 1.f);
    __shared__ float pl[64];
    pl[lane] = pc;
    __syncthreads();
    if (lane < NCLS) {
        float o = lin_b[lane];
#pragma unroll 8
        for (int c = 0; c < 64; ++c) o += pl[c] * lin_w[c * NCLS + lane];
        out[g * NCLS + lane] = o;
    }
}

// ---------------------------------------------------------------------------
extern "C" void kernel_launch(void* const* d_in, const int* in_sizes, int n_in,
                              void* d_out, int out_size, void* d_ws, size_t ws_size,
                              hipStream_t stream) {
    const float* x     = (const float*)d_in[0];
    const int*   ei    = (const int*)d_in[1];
    const int*   batch = (const int*)d_in[2];
    const float* Wl1   = (const float*)d_in[3];
    const float* Wr1   = (const float*)d_in[4];
    const float* att1  = (const float*)d_in[5];
    const float* b1    = (const float*)d_in[6];
    const float* Wl2   = (const float*)d_in[7];
    const float* Wr2   = (const float*)d_in[8];
    const float* att2  = (const float*)d_in[9];
    const float* b2    = (const float*)d_in[10];
    const float* lin_w = (const float*)d_in[11];
    const float* lin_b = (const float*)d_in[12];
    float* out = (float*)d_out;

    const int N_ = in_sizes[0] / F_IN;   // 50000
    const int E_ = in_sizes[1] / 2;      // 800000

    // Workspace layout (all intermediates bf16)
    unsigned short* B    = (unsigned short*)d_ws;       // xr1 -> h1 in place (N x 128); h2 reuses first N x 64
    unsigned short* xl1b = B + (long)N_ * 128;          // N x 128
    unsigned short* xl2b = xl1b + (long)N_ * 128;       // N x 64
    unsigned short* xr2b = xl2b + (long)N_ * 64;        // N x 64
    int* deg     = (int*)(xr2b + (long)N_ * 64);        // N
    int* rs      = deg + N_;                            // N+1
    int* cursor  = rs + N_ + 1;                         // N
    int* csr_src = cursor + N_;                         // E
    int* gstart  = csr_src + E_;                        // NG+1
    int* rs_part = gstart + NG + 1;                     // N
    int* blksum  = rs_part + N_;                        // 256
    unsigned short* h2 = B;

    const int nblk = (N_ + 255) / 256;   // 196 (must be <= 256)
    const int cblk = (E_ + 255) / 256;   // 3125
    const int csh  = 391;                // scatter blocks per shard: 391*256*8 > E

    // D1: zero degree counters
    hipMemsetAsync(deg, 0, (size_t)N_ * sizeof(int), stream);
    // D2: unsharded count + graph bounds
    count_gbound_kernel<<<cblk + nblk, 256, 0, stream>>>(ei, deg, batch, gstart,
                                                         E_, N_, cblk);
    // D3/D4: device-wide scan
    scan_local_kernel<<<nblk, 256, 0, stream>>>(deg, rs_part, blksum, N_);
    scan_final_kernel<<<nblk, 256, 0, stream>>>(rs_part, blksum, rs, cursor, N_, E_, nblk);
    // D5: XCD-sharded scatter (CSR fill)
    scatter_kernel<<<csh * 8, 256, 0, stream>>>(ei, cursor, csr_src, E_, N_, csh);
    // D6: GEMM1 -> xl1 (bf16), xr1 (bf16)
    gemm1_kernel<<<(N_ + 7) / 8, 256, 0, stream>>>(x, Wl1, Wr1, xl1b, B, N_);
    // D7: GAT layer 1 (head-merged, all-bf16), h1 in place over B
    {
        int blocks = (int)(((long)N_ * 64 + 255) / 256);
        gat1_kernel<<<blocks, 256, 0, stream>>>(xl1b, B, att1, b1, rs, csr_src, N_);
    }
    // D8: GEMM2 -> xl2 (bf16), xr2 (bf16)
    gemm2_kernel<<<(N_ + 7) / 8, 128, 0, stream>>>(B, Wl2, Wr2, xl2b, xr2b, N_);
    // D9: GAT layer 2 (all-bf16) -> h2 (bf16)
    {
        int blocks = (int)(((long)N_ * 64 + 255) / 256);
        gat2_kernel<<<blocks, 256, 0, stream>>>(xl2b, xr2b, att2, b2, rs, csr_src, h2, N_);
    }
    // D10: segmented mean-pool + classifier
    pool_final_kernel<<<NG, 64, 0, stream>>>(h2, gstart, lin_w, lin_b, out);
}

// Round 17
// 245.005 us; speedup vs baseline: 5.3254x; 5.3254x over previous
//
#include <hip/hip_runtime.h>
#include <hip/hip_bf16.h>

#define F_IN 64
#define HID 64
#define NCLS 10
#define NG 512

// bf16 helpers (RNE pack, cheap unpack)
__device__ __forceinline__ unsigned short f2bf(float f) {
    unsigned int u = __float_as_uint(f);
    unsigned int r = (u + 0x7fffu + ((u >> 16) & 1u)) >> 16;
    return (unsigned short)r;
}
__device__ __forceinline__ float bf2f(unsigned short h) {
    return __uint_as_float(((unsigned int)h) << 16);
}
__device__ __forceinline__ float4 bf4(ushort4 u) {
    return make_float4(bf2f(u.x), bf2f(u.y), bf2f(u.z), bf2f(u.w));
}

// ---------------------------------------------------------------------------
// Fused: UNsharded count + gbound.
__global__ void count_gbound_kernel(const int* __restrict__ ei, int* __restrict__ deg,
                                    const int* __restrict__ batch, int* __restrict__ gstart,
                                    int E_, int N_, int cblk) {
    int b = blockIdx.x;
    if (b < cblk) {
        int e = b * 256 + threadIdx.x;
        if (e < E_) atomicAdd(&deg[ei[E_ + e]], 1);
    } else {
        int i = (b - cblk) * 256 + threadIdx.x;
        if (i >= N_) return;
        int bi = batch[i];
        int bprev = (i == 0) ? -1 : batch[i - 1];
        for (int g = bprev + 1; g <= bi; ++g) gstart[g] = i;
        if (i == N_ - 1)
            for (int g = bi + 1; g <= NG; ++g) gstart[g] = N_;
    }
}

// ---------------------------------------------------------------------------
__global__ void scan_local_kernel(const int* __restrict__ deg, int* __restrict__ rs_part,
                                  int* __restrict__ blksum, int N_) {
    __shared__ int tmp[256];
    int t = threadIdx.x;
    int i = blockIdx.x * 256 + t;
    int v = (i < N_) ? deg[i] : 0;
    tmp[t] = v;
    __syncthreads();
    for (int off = 1; off < 256; off <<= 1) {
        int add = (t >= off) ? tmp[t - off] : 0;
        __syncthreads();
        tmp[t] += add;
        __syncthreads();
    }
    if (i < N_) rs_part[i] = tmp[t] - v;
    if (t == 255) blksum[blockIdx.x] = tmp[255];
}

__global__ void scan_final_kernel(const int* __restrict__ rs_part,
                                  const int* __restrict__ blksum,
                                  int* __restrict__ rs, int* __restrict__ cursor,
                                  int N_, int E_, int nblk) {
    __shared__ int tmp[256];
    int t = threadIdx.x;
    int b = blockIdx.x;
    tmp[t] = (t < b && t < nblk) ? blksum[t] : 0;
    __syncthreads();
    for (int off = 128; off > 0; off >>= 1) {
        if (t < off) tmp[t] += tmp[t + off];
        __syncthreads();
    }
    int off0 = tmp[0];
    int i = b * 256 + t;
    if (i < N_) {
        int v = rs_part[i] + off0;
        rs[i] = v;
        cursor[i] = v;
    }
    if (i == 0) rs[N_] = E_;
}

// ---------------------------------------------------------------------------
// XCD-sharded scatter (verified win, R13->R14).
__global__ void scatter_kernel(const int* __restrict__ ei, int* __restrict__ cursor,
                               int* __restrict__ csr_src, int E_, int N_, int csh) {
    int shard = blockIdx.x & 7;
    int chunk = blockIdx.x >> 3;
    int slice = (N_ + 7) >> 3;
    int lo = shard * slice, hi = min(N_, lo + slice);
    int stride = csh * 256;
    for (int e = chunk * 256 + threadIdx.x; e < E_; e += stride) {
        int d = ei[E_ + e];
        if (d >= lo && d < hi) {
            int pos = atomicAdd(&cursor[d], 1);
            csr_src[pos] = ei[e];
        }
    }
}

// ---------------------------------------------------------------------------
// GEMM1: x @ Wl1 -> xl1 (bf16), @ Wr1 -> xr1 (bf16).
// ROUND-15 scalar-k version (R16's k-tile x4 caused a scratch-traffic storm:
// 2.55 GB WRITE_SIZE, 1106 us — do not re-tile this kernel).
__global__ void gemm1_kernel(const float* __restrict__ x,
                             const float* __restrict__ Wl,
                             const float* __restrict__ Wr,
                             unsigned short* __restrict__ xlb,
                             unsigned short* __restrict__ xrb,
                             int N_) {
    __shared__ float xs[8 * 64];
    int r0 = blockIdx.x * 8;
    int t = threadIdx.x;
    for (int i = t; i < 8 * 64; i += 256) {
        int r = i >> 6;
        xs[i] = (r0 + r < N_) ? x[(long)(r0 + r) * 64 + (i & 63)] : 0.f;
    }
    __syncthreads();
    const float* W = (t < 128) ? Wl : Wr;
    int col = t & 127;
    float acc[8] = {0.f, 0.f, 0.f, 0.f, 0.f, 0.f, 0.f, 0.f};
    for (int k = 0; k < 64; ++k) {
        float w = W[k * 128 + col];
#pragma unroll
        for (int r = 0; r < 8; ++r) acc[r] += xs[r * 64 + k] * w;
    }
    unsigned short* out = (t < 128) ? xlb : xrb;
#pragma unroll
    for (int r = 0; r < 8; ++r)
        if (r0 + r < N_) out[(long)(r0 + r) * 128 + col] = f2bf(acc[r]);
}

// ---------------------------------------------------------------------------
// GEMM2: h1 (bf16) @ Wl2 -> xl2 (bf16), @ Wr2 -> xr2 (bf16).
// ROUND-15 scalar-k version (see gemm1 note).
__global__ void gemm2_kernel(const unsigned short* __restrict__ h1,
                             const float* __restrict__ Wl,
                             const float* __restrict__ Wr,
                             unsigned short* __restrict__ xlb,
                             unsigned short* __restrict__ xrb,
                             int N_) {
    __shared__ float hs[8 * 128];
    int r0 = blockIdx.x * 8;
    int t = threadIdx.x;
    for (int j = t; j < 256; j += 128) {
        int row = j >> 5, c4 = j & 31;
        float4 v = make_float4(0.f, 0.f, 0.f, 0.f);
        if (r0 + row < N_)
            v = bf4(*(const ushort4*)(h1 + (long)(r0 + row) * 128 + c4 * 4));
        *(float4*)(hs + row * 128 + c4 * 4) = v;
    }
    __syncthreads();
    const float* W = (t < 64) ? Wl : Wr;
    int col = t & 63;
    float acc[8] = {0.f, 0.f, 0.f, 0.f, 0.f, 0.f, 0.f, 0.f};
    for (int k = 0; k < 128; ++k) {
        float w = W[k * 64 + col];
#pragma unroll
        for (int r = 0; r < 8; ++r) acc[r] += hs[r * 128 + k] * w;
    }
    unsigned short* out = (t < 64) ? xlb : xrb;
#pragma unroll
    for (int r = 0; r < 8; ++r)
        if (r0 + r < N_) out[(long)(r0 + r) * 64 + col] = f2bf(acc[r]);
}

// ---------------------------------------------------------------------------
// Fused GATv2 layer 1, HEAD-MERGED, all-bf16. Main loop = full 4-edge groups
// with no masks + 32-bit gather offsets; one masked tail group.
__global__ void gat1_kernel(const unsigned short* __restrict__ xlb,
                            unsigned short* __restrict__ xrb,  // in: xr1, out: h1
                            const float* __restrict__ att,
                            const float* __restrict__ b1,
                            const int* __restrict__ rs,
                            const int* __restrict__ csr_src,
                            int N_) {
    int d = (int)(((long)blockIdx.x * blockDim.x + threadIdx.x) >> 6);
    int lane = threadIdx.x & 63;
    if (d >= N_) return;
    int slot = lane >> 5;     // 0..1
    int c8 = lane & 31;       // channel group: channels c8*4..+3 of 128
    unsigned coff = (unsigned)(c8 << 2);
    long rowoff = (long)d * 128 + c8 * 4;
    const float4 xr4 = bf4(*(const ushort4*)(xrb + rowoff));
    const float4 at4 = *(const float4*)(att + c8 * 4);

    int k0 = rs[d], k1 = rs[d + 1];
    int cnt = k1 - k0 + 1;

    float4 acc = make_float4(0.f, 0.f, 0.f, 0.f);
    float den = 0.f;
    for (int c0 = 0; c0 < cnt; c0 += 64) {
        int wl = c0 + lane;
        int myidx = (wl >= 1 && wl < cnt) ? csr_src[k0 + wl - 1] : d;
        int lim = min(64, cnt - c0);
        int pfull = lim & ~3;
        int p = 0;
        for (; p < pfull; p += 4) {      // all 4 edges valid: no masks
            int s0 = __shfl(myidx, p + slot, 64);
            int s1 = __shfl(myidx, p + 2 + slot, 64);
            float4 a0 = bf4(*(const ushort4*)(xlb + (((unsigned)s0 << 7) + coff)));
            float4 a1 = bf4(*(const ushort4*)(xlb + (((unsigned)s1 << 7) + coff)));
            float t, p0, p1;
            t = a0.x + xr4.x; t = fmaxf(t, 0.2f * t); p0  = at4.x * t;
            t = a0.y + xr4.y; t = fmaxf(t, 0.2f * t); p0 += at4.y * t;
            t = a0.z + xr4.z; t = fmaxf(t, 0.2f * t); p0 += at4.z * t;
            t = a0.w + xr4.w; t = fmaxf(t, 0.2f * t); p0 += at4.w * t;
            t = a1.x + xr4.x; t = fmaxf(t, 0.2f * t); p1  = at4.x * t;
            t = a1.y + xr4.y; t = fmaxf(t, 0.2f * t); p1 += at4.y * t;
            t = a1.z + xr4.z; t = fmaxf(t, 0.2f * t); p1 += at4.z * t;
            t = a1.w + xr4.w; t = fmaxf(t, 0.2f * t); p1 += at4.w * t;
            p0 += __shfl_xor(p0, 1, 64);  p1 += __shfl_xor(p1, 1, 64);
            p0 += __shfl_xor(p0, 2, 64);  p1 += __shfl_xor(p1, 2, 64);
            p0 += __shfl_xor(p0, 4, 64);  p1 += __shfl_xor(p1, 4, 64);
            p0 += __shfl_xor(p0, 8, 64);  p1 += __shfl_xor(p1, 8, 64);
            float w0 = __expf(p0);
            float w1 = __expf(p1);
            acc.x += w0 * a0.x + w1 * a1.x;
            acc.y += w0 * a0.y + w1 * a1.y;
            acc.z += w0 * a0.z + w1 * a1.z;
            acc.w += w0 * a0.w + w1 * a1.w;
            den += w0 + w1;
        }
        if (p < lim) {                   // masked tail group
            int e0 = p + slot;
            int s0 = __shfl(myidx, e0, 64);
            float4 a0 = bf4(*(const ushort4*)(xlb + (((unsigned)s0 << 7) + coff)));
            float t, p0;
            t = a0.x + xr4.x; t = fmaxf(t, 0.2f * t); p0  = at4.x * t;
            t = a0.y + xr4.y; t = fmaxf(t, 0.2f * t); p0 += at4.y * t;
            t = a0.z + xr4.z; t = fmaxf(t, 0.2f * t); p0 += at4.z * t;
            t = a0.w + xr4.w; t = fmaxf(t, 0.2f * t); p0 += at4.w * t;
            p0 += __shfl_xor(p0, 1, 64);
            p0 += __shfl_xor(p0, 2, 64);
            p0 += __shfl_xor(p0, 4, 64);
            p0 += __shfl_xor(p0, 8, 64);
            float w0 = (e0 < lim) ? __expf(p0) : 0.f;
            acc.x += w0 * a0.x; acc.y += w0 * a0.y;
            acc.z += w0 * a0.z; acc.w += w0 * a0.w;
            den += w0;
            if (p + 2 < lim) {           // wave-uniform: 2nd depth exists
                int e1 = p + 2 + slot;
                int s1 = __shfl(myidx, e1, 64);
                float4 a1 = bf4(*(const ushort4*)(xlb + (((unsigned)s1 << 7) + coff)));
                float p1;
                t = a1.x + xr4.x; t = fmaxf(t, 0.2f * t); p1  = at4.x * t;
                t = a1.y + xr4.y; t = fmaxf(t, 0.2f * t); p1 += at4.y * t;
                t = a1.z + xr4.z; t = fmaxf(t, 0.2f * t); p1 += at4.z * t;
                t = a1.w + xr4.w; t = fmaxf(t, 0.2f * t); p1 += at4.w * t;
                p1 += __shfl_xor(p1, 1, 64);
                p1 += __shfl_xor(p1, 2, 64);
                p1 += __shfl_xor(p1, 4, 64);
                p1 += __shfl_xor(p1, 8, 64);
                float w1 = (e1 < lim) ? __expf(p1) : 0.f;
                acc.x += w1 * a1.x; acc.y += w1 * a1.y;
                acc.z += w1 * a1.z; acc.w += w1 * a1.w;
                den += w1;
            }
        }
    }
    acc.x += __shfl_xor(acc.x, 32, 64);
    acc.y += __shfl_xor(acc.y, 32, 64);
    acc.z += __shfl_xor(acc.z, 32, 64);
    acc.w += __shfl_xor(acc.w, 32, 64);
    den   += __shfl_xor(den, 32, 64);
    if (slot == 0) {
        const float4 b4 = *(const float4*)(b1 + c8 * 4);
        float inv = 1.f / den;
        float4 v;
        v.x = acc.x * inv + b4.x; v.x = (v.x > 0.f) ? v.x : __expf(v.x) - 1.f;
        v.y = acc.y * inv + b4.y; v.y = (v.y > 0.f) ? v.y : __expf(v.y) - 1.f;
        v.z = acc.z * inv + b4.z; v.z = (v.z > 0.f) ? v.z : __expf(v.z) - 1.f;
        v.w = acc.w * inv + b4.w; v.w = (v.w > 0.f) ? v.w : __expf(v.w) - 1.f;
        ushort4 o;
        o.x = f2bf(v.x); o.y = f2bf(v.y); o.z = f2bf(v.z); o.w = f2bf(v.w);
        *(ushort4*)(xrb + rowoff) = o;   // h1 in place (bf16)
    }
}

// ---------------------------------------------------------------------------
// Fused GATv2 layer 2, all-bf16. Same main/tail split (4 slots, groups of 8).
__global__ void gat2_kernel(const unsigned short* __restrict__ xlb,
                            const unsigned short* __restrict__ xrb,
                            const float* __restrict__ att,
                            const float* __restrict__ b2,
                            const int* __restrict__ rs,
                            const int* __restrict__ csr_src,
                            unsigned short* __restrict__ h2,
                            int N_) {
    int d = (int)(((long)blockIdx.x * blockDim.x + threadIdx.x) >> 6);
    int lane = threadIdx.x & 63;
    if (d >= N_) return;
    int g = lane >> 4;        // 0..3
    int c4 = lane & 15;
    unsigned coff = (unsigned)(c4 << 2);
    long rowoff = (long)d * 64 + c4 * 4;
    const float4 xr4 = bf4(*(const ushort4*)(xrb + rowoff));
    const float4 at4 = *(const float4*)(att + c4 * 4);

    int k0 = rs[d], k1 = rs[d + 1];
    int cnt = k1 - k0 + 1;

    float4 acc = make_float4(0.f, 0.f, 0.f, 0.f);
    float den = 0.f;
    for (int c0 = 0; c0 < cnt; c0 += 64) {
        int wl = c0 + lane;
        int myidx = (wl >= 1 && wl < cnt) ? csr_src[k0 + wl - 1] : d;
        int lim = min(64, cnt - c0);
        int pfull = lim & ~7;
        int p = 0;
        for (; p < pfull; p += 8) {      // 8 valid edges: no masks
            int s0 = __shfl(myidx, p + g, 64);
            int s1 = __shfl(myidx, p + 4 + g, 64);
            float4 a0 = bf4(*(const ushort4*)(xlb + (((unsigned)s0 << 6) + coff)));
            float4 a1 = bf4(*(const ushort4*)(xlb + (((unsigned)s1 << 6) + coff)));
            float t, p0, p1;
            t = a0.x + xr4.x; t = fmaxf(t, 0.2f * t); p0  = at4.x * t;
            t = a0.y + xr4.y; t = fmaxf(t, 0.2f * t); p0 += at4.y * t;
            t = a0.z + xr4.z; t = fmaxf(t, 0.2f * t); p0 += at4.z * t;
            t = a0.w + xr4.w; t = fmaxf(t, 0.2f * t); p0 += at4.w * t;
            t = a1.x + xr4.x; t = fmaxf(t, 0.2f * t); p1  = at4.x * t;
            t = a1.y + xr4.y; t = fmaxf(t, 0.2f * t); p1 += at4.y * t;
            t = a1.z + xr4.z; t = fmaxf(t, 0.2f * t); p1 += at4.z * t;
            t = a1.w + xr4.w; t = fmaxf(t, 0.2f * t); p1 += at4.w * t;
            p0 += __shfl_xor(p0, 1, 64);  p1 += __shfl_xor(p1, 1, 64);
            p0 += __shfl_xor(p0, 2, 64);  p1 += __shfl_xor(p1, 2, 64);
            p0 += __shfl_xor(p0, 4, 64);  p1 += __shfl_xor(p1, 4, 64);
            p0 += __shfl_xor(p0, 8, 64);  p1 += __shfl_xor(p1, 8, 64);
            float w0 = __expf(p0);
            float w1 = __expf(p1);
            acc.x += w0 * a0.x + w1 * a1.x;
            acc.y += w0 * a0.y + w1 * a1.y;
            acc.z += w0 * a0.z + w1 * a1.z;
            acc.w += w0 * a0.w + w1 * a1.w;
            den += w0 + w1;
        }
        if (p < lim) {                   // masked tail group
            int e0 = p + g;
            int s0 = __shfl(myidx, e0, 64);
            float4 a0 = bf4(*(const ushort4*)(xlb + (((unsigned)s0 << 6) + coff)));
            float t, p0;
            t = a0.x + xr4.x; t = fmaxf(t, 0.2f * t); p0  = at4.x * t;
            t = a0.y + xr4.y; t = fmaxf(t, 0.2f * t); p0 += at4.y * t;
            t = a0.z + xr4.z; t = fmaxf(t, 0.2f * t); p0 += at4.z * t;
            t = a0.w + xr4.w; t = fmaxf(t, 0.2f * t); p0 += at4.w * t;
            p0 += __shfl_xor(p0, 1, 64);
            p0 += __shfl_xor(p0, 2, 64);
            p0 += __shfl_xor(p0, 4, 64);
            p0 += __shfl_xor(p0, 8, 64);
            float w0 = (e0 < lim) ? __expf(p0) : 0.f;
            acc.x += w0 * a0.x; acc.y += w0 * a0.y;
            acc.z += w0 * a0.z; acc.w += w0 * a0.w;
            den += w0;
            if (p + 4 < lim) {           // wave-uniform 2nd depth
                int e1 = p + 4 + g;
                int s1 = __shfl(myidx, e1, 64);
                float4 a1 = bf4(*(const ushort4*)(xlb + (((unsigned)s1 << 6) + coff)));
                float p1;
                t = a1.x + xr4.x; t = fmaxf(t, 0.2f * t); p1  = at4.x * t;
                t = a1.y + xr4.y; t = fmaxf(t, 0.2f * t); p1 += at4.y * t;
                t = a1.z + xr4.z; t = fmaxf(t, 0.2f * t); p1 += at4.z * t;
                t = a1.w + xr4.w; t = fmaxf(t, 0.2f * t); p1 += at4.w * t;
                p1 += __shfl_xor(p1, 1, 64);
                p1 += __shfl_xor(p1, 2, 64);
                p1 += __shfl_xor(p1, 4, 64);
                p1 += __shfl_xor(p1, 8, 64);
                float w1 = (e1 < lim) ? __expf(p1) : 0.f;
                acc.x += w1 * a1.x; acc.y += w1 * a1.y;
                acc.z += w1 * a1.z; acc.w += w1 * a1.w;
                den += w1;
            }
        }
    }
#pragma unroll
    for (int m = 16; m < 64; m <<= 1) {
        acc.x += __shfl_xor(acc.x, m, 64);
        acc.y += __shfl_xor(acc.y, m, 64);
        acc.z += __shfl_xor(acc.z, m, 64);
        acc.w += __shfl_xor(acc.w, m, 64);
        den   += __shfl_xor(den, m, 64);
    }
    if (g == 0) {
        const float4 b4 = *(const float4*)(b2 + c4 * 4);
        float inv = 1.f / den;
        ushort4 o;
        o.x = f2bf(acc.x * inv + b4.x);
        o.y = f2bf(acc.y * inv + b4.y);
        o.z = f2bf(acc.z * inv + b4.z);
        o.w = f2bf(acc.w * inv + b4.w);
        *(ushort4*)(h2 + rowoff) = o;
    }
}

// ---------------------------------------------------------------------------
// Segmented mean-pool (h2 bf16) + 64x10 classifier.
__global__ void pool_final_kernel(const unsigned short* __restrict__ h2,
                                  const int* __restrict__ gstart,
                                  const float* __restrict__ lin_w,
                                  const float* __restrict__ lin_b,
                                  float* __restrict__ out) {
    int g = blockIdx.x;
    int lane = threadIdx.x;
    int s = gstart[g], e = gstart[g + 1];
    float acc = 0.f;
    int i = s;
    for (; i + 3 < e; i += 4) {
        float v0 = bf2f(h2[(long)i * 64 + lane]);
        float v1 = bf2f(h2[(long)(i + 1) * 64 + lane]);
        float v2 = bf2f(h2[(long)(i + 2) * 64 + lane]);
        float v3 = bf2f(h2[(long)(i + 3) * 64 + lane]);
        acc += (v0 + v1) + (v2 + v3);
    }
    for (; i < e; ++i) acc += bf2f(h2[(long)i * 64 + lane]);
    float pc = acc / fmaxf((float)(e - s), 1.f);
    __shared__ float pl[64];
    pl[lane] = pc;
    __syncthreads();
    if (lane < NCLS) {
        float o = lin_b[lane];
#pragma unroll 8
        for (int c = 0; c < 64; ++c) o += pl[c] * lin_w[c * NCLS + lane];
        out[g * NCLS + lane] = o;
    }
}

// ---------------------------------------------------------------------------
extern "C" void kernel_launch(void* const* d_in, const int* in_sizes, int n_in,
                              void* d_out, int out_size, void* d_ws, size_t ws_size,
                              hipStream_t stream) {
    const float* x     = (const float*)d_in[0];
    const int*   ei    = (const int*)d_in[1];
    const int*   batch = (const int*)d_in[2];
    const float* Wl1   = (const float*)d_in[3];
    const float* Wr1   = (const float*)d_in[4];
    const float* att1  = (const float*)d_in[5];
    const float* b1    = (const float*)d_in[6];
    const float* Wl2   = (const float*)d_in[7];
    const float* Wr2   = (const float*)d_in[8];
    const float* att2  = (const float*)d_in[9];
    const float* b2    = (const float*)d_in[10];
    const float* lin_w = (const float*)d_in[11];
    const float* lin_b = (const float*)d_in[12];
    float* out = (float*)d_out;

    const int N_ = in_sizes[0] / F_IN;   // 50000
    const int E_ = in_sizes[1] / 2;      // 800000

    // Workspace layout (all intermediates bf16)
    unsigned short* B    = (unsigned short*)d_ws;       // xr1 -> h1 in place (N x 128); h2 reuses first N x 64
    unsigned short* xl1b = B + (long)N_ * 128;          // N x 128
    unsigned short* xl2b = xl1b + (long)N_ * 128;       // N x 64
    unsigned short* xr2b = xl2b + (long)N_ * 64;        // N x 64
    int* deg     = (int*)(xr2b + (long)N_ * 64);        // N
    int* rs      = deg + N_;                            // N+1
    int* cursor  = rs + N_ + 1;                         // N
    int* csr_src = cursor + N_;                         // E
    int* gstart  = csr_src + E_;                        // NG+1
    int* rs_part = gstart + NG + 1;                     // N
    int* blksum  = rs_part + N_;                        // 256
    unsigned short* h2 = B;

    const int nblk = (N_ + 255) / 256;   // 196 (must be <= 256)
    const int cblk = (E_ + 255) / 256;   // 3125
    const int csh  = 391;                // scatter blocks per shard: 391*256*8 > E

    // D1: zero degree counters
    hipMemsetAsync(deg, 0, (size_t)N_ * sizeof(int), stream);
    // D2: unsharded count + graph bounds
    count_gbound_kernel<<<cblk + nblk, 256, 0, stream>>>(ei, deg, batch, gstart,
                                                         E_, N_, cblk);
    // D3/D4: device-wide scan
    scan_local_kernel<<<nblk, 256, 0, stream>>>(deg, rs_part, blksum, N_);
    scan_final_kernel<<<nblk, 256, 0, stream>>>(rs_part, blksum, rs, cursor, N_, E_, nblk);
    // D5: XCD-sharded scatter (CSR fill)
    scatter_kernel<<<csh * 8, 256, 0, stream>>>(ei, cursor, csr_src, E_, N_, csh);
    // D6: GEMM1 -> xl1 (bf16), xr1 (bf16)
    gemm1_kernel<<<(N_ + 7) / 8, 256, 0, stream>>>(x, Wl1, Wr1, xl1b, B, N_);
    // D7: GAT layer 1 (head-merged, all-bf16), h1 in place over B
    {
        int blocks = (int)(((long)N_ * 64 + 255) / 256);
        gat1_kernel<<<blocks, 256, 0, stream>>>(xl1b, B, att1, b1, rs, csr_src, N_);
    }
    // D8: GEMM2 -> xl2 (bf16), xr2 (bf16)
    gemm2_kernel<<<(N_ + 7) / 8, 128, 0, stream>>>(B, Wl2, Wr2, xl2b, xr2b, N_);
    // D9: GAT layer 2 (all-bf16) -> h2 (bf16)
    {
        int blocks = (int)(((long)N_ * 64 + 255) / 256);
        gat2_kernel<<<blocks, 256, 0, stream>>>(xl2b, xr2b, att2, b2, rs, csr_src, h2, N_);
    }
    // D10: segmented mean-pool + classifier
    pool_final_kernel<<<NG, 64, 0, stream>>>(h2, gstart, lin_w, lin_b, out);
}